// Round 7
// baseline (408.540 us; speedup 1.0000x reference)
//
#include <hip/hip_runtime.h>
#include <math.h>

#define ND 512
#define NK 32

typedef __attribute__((ext_vector_type(8))) short short8;
typedef __attribute__((ext_vector_type(4))) float f32x4;
typedef __attribute__((address_space(1))) const unsigned int glds_src;
typedef __attribute__((address_space(3))) unsigned int glds_dst;

__device__ inline unsigned short f2bf(float x) {
  unsigned u = __float_as_uint(x);
  unsigned r = (u + 0x7fffu + ((u >> 16) & 1u)) >> 16;  // RNE
  return (unsigned short)r;
}
__device__ inline float bf2f(unsigned short h) {
  return __uint_as_float(((unsigned)h) << 16);
}
__device__ inline void gload_lds16(const void* g, void* l) {
  __builtin_amdgcn_global_load_lds((glds_src*)g, (glds_dst*)l, 16, 0, 0);
}

// bijective XCD chunking (m204)
__device__ inline int xcd_swz(int orig, int nwg) {
  const int q = nwg >> 3, r = nwg & 7;
  const int xcd = orig & 7, pos = orig >> 3;
  return (xcd < r ? xcd * (q + 1) : r * (q + 1) + (xcd - r) * q) + pos;
}

// ---------------- mask dtype detection ----------------
__global__ void detect_mask_kernel(const unsigned int* __restrict__ m, int nwords,
                                   int* __restrict__ flag) {
  int local = 0;
  for (int i = blockIdx.x * blockDim.x + threadIdx.x; i < nwords;
       i += gridDim.x * blockDim.x) {
    if (m[i] > 1u) local = 1;
  }
  if (__any(local)) {
    if ((threadIdx.x & 63) == 0) atomicOr(flag, 1);
  }
}

// ---------------- fused panel converter (prev + W1 + Wa) ----------------
// per k-block (128 B): 4 groups of [hi 16B | lo 16B], XOR-swizzle ((row&7)<<4).
__device__ inline void conv_chunk(const float* __restrict__ src,
                                  unsigned char* __restrict__ dst,
                                  int rows_src, int Kd, long long c) {
  const int cpr = Kd * 4;
  const int r = (int)(c / cpr);
  const int rem = (int)(c % cpr);
  const int kb = rem >> 2;
  const int s = rem & 3;
  const int sw = (r & 7) << 4;
  unsigned short h[8], l[8];
  if (r < rows_src) {
    const float* p = src + (size_t)r * (Kd * 32) + kb * 32 + s * 8;
    #pragma unroll
    for (int j = 0; j < 8; j++) {
      const float v = p[j];
      h[j] = f2bf(v);
      l[j] = f2bf(v - bf2f(h[j]));
    }
  } else {
    #pragma unroll
    for (int j = 0; j < 8; j++) { h[j] = 0; l[j] = 0; }
  }
  uint4 hv, lv;
  hv.x = (unsigned)h[0] | ((unsigned)h[1] << 16);
  hv.y = (unsigned)h[2] | ((unsigned)h[3] << 16);
  hv.z = (unsigned)h[4] | ((unsigned)h[5] << 16);
  hv.w = (unsigned)h[6] | ((unsigned)h[7] << 16);
  lv.x = (unsigned)l[0] | ((unsigned)l[1] << 16);
  lv.y = (unsigned)l[2] | ((unsigned)l[3] << 16);
  lv.z = (unsigned)l[4] | ((unsigned)l[5] << 16);
  lv.w = (unsigned)l[6] | ((unsigned)l[7] << 16);
  unsigned char* rowb = dst + (size_t)r * (Kd * 128) + kb * 128;
  *(uint4*)(rowb + ((s * 32) ^ sw)) = hv;
  *(uint4*)(rowb + ((s * 32 + 16) ^ sw)) = lv;
}

__global__ void convert_panels3(const float* __restrict__ prev, unsigned char* __restrict__ prevP,
                                int Np, int Mp,
                                const float* __restrict__ W1, unsigned char* __restrict__ W1P,
                                const float* __restrict__ Wa, unsigned char* __restrict__ WaP) {
  const long long c0 = (long long)Mp * 64;          // prev chunks (Kd=16)
  const long long c1 = c0 + 512 * 64;               // + W1 chunks (Kd=16)
  const long long c2 = c1 + 512 * 128;              // + Wa chunks (Kd=32)
  for (long long c = (long long)blockIdx.x * blockDim.x + threadIdx.x; c < c2;
       c += (long long)gridDim.x * blockDim.x) {
    if (c < c0)      conv_chunk(prev, prevP, Np, 16, c);
    else if (c < c1) conv_chunk(W1, W1P, 512, 16, c - c0);
    else             conv_chunk(Wa, WaP, 512, 32, c - c1);
  }
}

// ---------------- split-bf16 MFMA GEMM on panel images (gemm2) ----------
template<bool SPLIT, bool TANH, bool LH>
__global__ __launch_bounds__(256, 3) void gemm_mfma(
    const unsigned char* __restrict__ A1, const unsigned char* __restrict__ A2,
    const unsigned char* __restrict__ B, float* __restrict__ C,
    int M, int N, int KB)
{
  __shared__ unsigned char AsP[16384];
  __shared__ unsigned char BsP[16384];
  const int tid = threadIdx.x;
  const int lane = tid & 63;
  const int wv = tid >> 6;
  const int wr = wv >> 1, wc = wv & 1;
  const int wgid = xcd_swz(blockIdx.x, gridDim.x);
  const int bm = (wgid >> 2) * 128, bn = (wgid & 3) * 128;
  const size_t brstride = (size_t)KB * 128;
  const size_t arstride = SPLIT ? 2048 : (size_t)KB * 128;

  f32x4 acc[4][4];
  #pragma unroll
  for (int i = 0; i < 4; i++)
    #pragma unroll
    for (int j = 0; j < 4; j++) acc[i][j] = (f32x4){0.f, 0.f, 0.f, 0.f};

  const int s16 = (lane >> 4) * 32;
  const int lrow0 = (wv << 3) + (lane >> 3);
  const int lbyte = (lane & 7) * 16;

  for (int kb = 0; kb < KB; kb++) {
    const unsigned char* Ab;
    int akb;
    if (SPLIT) { Ab = (kb < 16) ? A1 : A2; akb = kb & 15; }
    else       { Ab = A1; akb = kb; }
    #pragma unroll
    for (int i = 0; i < 4; i++) {
      const int lrow = i * 32 + lrow0;
      gload_lds16(Ab + (size_t)(bm + lrow) * arstride + (size_t)akb * 128 + lbyte,
                  AsP + i * 4096 + wv * 1024);
      gload_lds16(B + (size_t)(bn + lrow) * brstride + (size_t)kb * 128 + lbyte,
                  BsP + i * 4096 + wv * 1024);
    }
    __syncthreads();

    short8 bh[4], bl[4];
    #pragma unroll
    for (int fn = 0; fn < 4; fn++) {
      const int row = wc * 64 + fn * 16 + (lane & 15);
      const int sw = (row & 7) << 4;
      bh[fn] = *(const short8*)(BsP + row * 128 + (s16 ^ sw));
      bl[fn] = *(const short8*)(BsP + row * 128 + ((s16 + 16) ^ sw));
    }
    #pragma unroll
    for (int fm = 0; fm < 4; fm++) {
      const int row = wr * 64 + fm * 16 + (lane & 15);
      const int sw = (row & 7) << 4;
      const short8 ah = *(const short8*)(AsP + row * 128 + (s16 ^ sw));
      short8 al;
      if (LH) al = *(const short8*)(AsP + row * 128 + ((s16 + 16) ^ sw));
      #pragma unroll
      for (int fn = 0; fn < 4; fn++) {
        acc[fm][fn] = __builtin_amdgcn_mfma_f32_16x16x32_bf16(ah, bh[fn], acc[fm][fn], 0, 0, 0);
        acc[fm][fn] = __builtin_amdgcn_mfma_f32_16x16x32_bf16(ah, bl[fn], acc[fm][fn], 0, 0, 0);
        if (LH)
          acc[fm][fn] = __builtin_amdgcn_mfma_f32_16x16x32_bf16(al, bh[fn], acc[fm][fn], 0, 0, 0);
      }
    }
    __syncthreads();
  }

  #pragma unroll
  for (int fm = 0; fm < 4; fm++) {
    #pragma unroll
    for (int fn = 0; fn < 4; fn++) {
      const int col = bn + wc * 64 + fn * 16 + (lane & 15);
      #pragma unroll
      for (int j = 0; j < 4; j++) {
        const int row = bm + wr * 64 + fm * 16 + (lane >> 4) * 4 + j;
        if (row < M) {
          float v = acc[fm][fn][j];
          if (TANH) v = tanhf(v);
          C[(size_t)row * N + col] = v;
        }
      }
    }
  }
}

// ---------------- panel encode of one float4 group ----------------
// grp 0: k = 4*lane..4*lane+3 ; grp 1: k = 256+4*lane..+3
__device__ inline void enc_store(unsigned char* __restrict__ rowp, int lane, int grp,
                                 float4 v, int sw) {
  const int k0 = grp * 256 + 4 * lane;
  const int kb = k0 >> 5;
  const int bu = (((k0 >> 3) & 3) << 5) + ((k0 & 7) << 1);
  const unsigned short h0 = f2bf(v.x), h1 = f2bf(v.y), h2 = f2bf(v.z), h3 = f2bf(v.w);
  const unsigned short l0 = f2bf(v.x - bf2f(h0)), l1 = f2bf(v.y - bf2f(h1)),
                       l2 = f2bf(v.z - bf2f(h2)), l3 = f2bf(v.w - bf2f(h3));
  uint2 hp, lp;
  hp.x = (unsigned)h0 | ((unsigned)h1 << 16);
  hp.y = (unsigned)h2 | ((unsigned)h3 << 16);
  lp.x = (unsigned)l0 | ((unsigned)l1 << 16);
  lp.y = (unsigned)l2 | ((unsigned)l3 << 16);
  *(uint2*)(rowp + kb * 128 + (bu ^ sw)) = hp;
  *(uint2*)(rowp + kb * 128 + ((bu | 16) ^ sw)) = lp;
}

// ---------------- mega attention: x-GEMM + scores + softmax + agg ------
// 16 rows/block, 512 thr / 8 waves.
// Phase 1: x[16][512] = prevP @ W1P^T (split-3 MFMA), operands gathered
//          directly from global/L2 (no LDS staging, no barriers).
// Phase 2: one wave per 2 rows, stream 32 neighbors once, online softmax,
//          everything in registers (mask pre-folded into a 32-bit ballot).
// Phase 3: encode agg rows to panel image with direct global stores.
__global__ __launch_bounds__(512, 4) void attn_mega(
    const unsigned char* __restrict__ prevP,  // [Mp,2048] panel
    const unsigned char* __restrict__ W1P,    // [512,2048] panel
    const float* __restrict__ neigh,          // [N,32,512]
    const void* __restrict__ mask,
    const int* __restrict__ mask_is_u8,
    unsigned char* __restrict__ aggP)         // [Mp,2048] panel
{
  __shared__ float x_s[16][516];
  const int tid = threadIdx.x;
  const int lane = tid & 63;
  const int w = tid >> 6;
  const int n0 = blockIdx.x * 16;

  // ---- phase 1 ----
  const int fr = lane & 15;
  const int s16 = (lane >> 4) * 32;
  const int sw1 = (fr & 7) << 4;     // n0, cg*128, w*16 all ≡ 0 mod 8
  const unsigned char* Arow = prevP + (size_t)(n0 + fr) * 2048;

  f32x4 acc[4];
  #pragma unroll
  for (int cg = 0; cg < 4; cg++) acc[cg] = (f32x4){0.f, 0.f, 0.f, 0.f};

  #pragma unroll 2
  for (int kb = 0; kb < 16; kb++) {
    const short8 ah = *(const short8*)(Arow + kb * 128 + (s16 ^ sw1));
    const short8 al = *(const short8*)(Arow + kb * 128 + ((s16 + 16) ^ sw1));
    #pragma unroll
    for (int cg = 0; cg < 4; cg++) {
      const unsigned char* Brow = W1P + (size_t)(cg * 128 + w * 16 + fr) * 2048;
      const short8 bh = *(const short8*)(Brow + kb * 128 + (s16 ^ sw1));
      const short8 bl = *(const short8*)(Brow + kb * 128 + ((s16 + 16) ^ sw1));
      acc[cg] = __builtin_amdgcn_mfma_f32_16x16x32_bf16(ah, bh, acc[cg], 0, 0, 0);
      acc[cg] = __builtin_amdgcn_mfma_f32_16x16x32_bf16(ah, bl, acc[cg], 0, 0, 0);
      acc[cg] = __builtin_amdgcn_mfma_f32_16x16x32_bf16(al, bh, acc[cg], 0, 0, 0);
    }
  }
  // C-map: row (local) = (lane>>4)*4+j, col = cg*128 + w*16 + (lane&15)
  #pragma unroll
  for (int cg = 0; cg < 4; cg++) {
    const int col = cg * 128 + w * 16 + fr;
    #pragma unroll
    for (int j = 0; j < 4; j++) x_s[(lane >> 4) * 4 + j][col] = acc[cg][j];
  }
  __syncthreads();

  // ---- phase 2: wave w owns rows 2w, 2w+1 ----
  const int gna = n0 + 2 * w, gnb = gna + 1;
  const float4 xA0 = *(const float4*)&x_s[2 * w][lane * 4];
  const float4 xA1 = *(const float4*)&x_s[2 * w][256 + lane * 4];
  const float4 xB0 = *(const float4*)&x_s[2 * w + 1][lane * 4];
  const float4 xB1 = *(const float4*)&x_s[2 * w + 1][256 + lane * 4];

  const int u8m = *mask_is_u8;
  int mva = 0, mvb = 0;
  if (lane < NK) {
    if (u8m) {
      mva = ((const unsigned char*)mask)[(size_t)gna * NK + lane];
      mvb = ((const unsigned char*)mask)[(size_t)gnb * NK + lane];
    } else {
      mva = ((const int*)mask)[(size_t)gna * NK + lane];
      mvb = ((const int*)mask)[(size_t)gnb * NK + lane];
    }
  }
  const unsigned mba = (unsigned)__ballot(mva != 0);
  const unsigned mbb = (unsigned)__ballot(mvb != 0);

  const float4* nba = (const float4*)(neigh + (size_t)gna * NK * ND);
  const float4* nbb = (const float4*)(neigh + (size_t)gnb * NK * ND);

  float ma = -3.4e38f, la = 0.f, mb = -3.4e38f, lb = 0.f;
  float4 aA0 = {0,0,0,0}, aA1 = {0,0,0,0}, aB0 = {0,0,0,0}, aB1 = {0,0,0,0};

  for (int j = 0; j < NK; j++) {
    const float4 va0 = nba[j * 128 + lane];
    const float4 va1 = nba[j * 128 + 64 + lane];
    const float4 vb0 = nbb[j * 128 + lane];
    const float4 vb1 = nbb[j * 128 + 64 + lane];
    float sa = va0.x * xA0.x + va0.y * xA0.y + va0.z * xA0.z + va0.w * xA0.w
             + va1.x * xA1.x + va1.y * xA1.y + va1.z * xA1.z + va1.w * xA1.w;
    float sb = vb0.x * xB0.x + vb0.y * xB0.y + vb0.z * xB0.z + vb0.w * xB0.w
             + vb1.x * xB1.x + vb1.y * xB1.y + vb1.z * xB1.z + vb1.w * xB1.w;
    #pragma unroll
    for (int off = 32; off; off >>= 1) {
      sa += __shfl_xor(sa, off);
      sb += __shfl_xor(sb, off);
    }
    if (!((mba >> j) & 1)) {
      const float mn = fmaxf(ma, sa);
      const float sc = __expf(ma - mn);
      const float c = __expf(sa - mn);
      la = la * sc + c;
      aA0.x = fmaf(aA0.x, sc, c * va0.x); aA0.y = fmaf(aA0.y, sc, c * va0.y);
      aA0.z = fmaf(aA0.z, sc, c * va0.z); aA0.w = fmaf(aA0.w, sc, c * va0.w);
      aA1.x = fmaf(aA1.x, sc, c * va1.x); aA1.y = fmaf(aA1.y, sc, c * va1.y);
      aA1.z = fmaf(aA1.z, sc, c * va1.z); aA1.w = fmaf(aA1.w, sc, c * va1.w);
      ma = mn;
    }
    if (!((mbb >> j) & 1)) {
      const float mn = fmaxf(mb, sb);
      const float sc = __expf(mb - mn);
      const float c = __expf(sb - mn);
      lb = lb * sc + c;
      aB0.x = fmaf(aB0.x, sc, c * vb0.x); aB0.y = fmaf(aB0.y, sc, c * vb0.y);
      aB0.z = fmaf(aB0.z, sc, c * vb0.z); aB0.w = fmaf(aB0.w, sc, c * vb0.w);
      aB1.x = fmaf(aB1.x, sc, c * vb1.x); aB1.y = fmaf(aB1.y, sc, c * vb1.y);
      aB1.z = fmaf(aB1.z, sc, c * vb1.z); aB1.w = fmaf(aB1.w, sc, c * vb1.w);
      mb = mn;
    }
  }
  const float ia = 1.f / la, ib = 1.f / lb;
  aA0.x *= ia; aA0.y *= ia; aA0.z *= ia; aA0.w *= ia;
  aA1.x *= ia; aA1.y *= ia; aA1.z *= ia; aA1.w *= ia;
  aB0.x *= ib; aB0.y *= ib; aB0.z *= ib; aB0.w *= ib;
  aB1.x *= ib; aB1.y *= ib; aB1.z *= ib; aB1.w *= ib;

  // ---- phase 3: panel-encode agg rows, direct global stores ----
  unsigned char* rpa = aggP + (size_t)gna * 2048;
  unsigned char* rpb = aggP + (size_t)gnb * 2048;
  enc_store(rpa, lane, 0, aA0, (gna & 7) << 4);
  enc_store(rpa, lane, 1, aA1, (gna & 7) << 4);
  enc_store(rpb, lane, 0, aB0, (gnb & 7) << 4);
  enc_store(rpb, lane, 1, aB1, (gnb & 7) << 4);
}

extern "C" void kernel_launch(void* const* d_in, const int* in_sizes, int n_in,
                              void* d_out, int out_size, void* d_ws, size_t ws_size,
                              hipStream_t stream) {
  const float* prev  = (const float*)d_in[0];   // [N, 512]
  const float* neigh = (const float*)d_in[1];   // [N, 32, 512]
  const void*  mask  = d_in[2];                 // [N, 32]
  const float* W1    = (const float*)d_in[3];   // [512, 512]
  const float* Wa    = (const float*)d_in[4];   // [512, 1024]
  float* out = (float*)d_out;
  const int N = in_sizes[0] / ND;               // 20000
  const int Mp = ((N + 127) / 128) * 128;       // 20096

  unsigned char* ws = (unsigned char*)d_ws;
  unsigned char* prevP = ws;                                 // Mp*2048
  unsigned char* aggP  = prevP + (size_t)Mp * 2048;          // Mp*2048
  unsigned char* W1P   = aggP + (size_t)Mp * 2048;           // 512*2048
  unsigned char* WaP   = W1P + (size_t)512 * 2048;           // 512*4096
  int*           flag  = (int*)(WaP + (size_t)512 * 4096);

  hipMemsetAsync(flag, 0, sizeof(int), stream);
  detect_mask_kernel<<<64, 256, 0, stream>>>((const unsigned int*)mask,
                                             (N * NK) / 4, flag);

  // pre-encode panel images (single launch)
  convert_panels3<<<2048, 256, 0, stream>>>(prev, prevP, N, Mp, W1, W1P, Wa, WaP);

  // x-GEMM + scores -> online softmax -> agg (neigh streamed once)
  attn_mega<<<N / 16, 512, 0, stream>>>(prevP, W1P, neigh, mask, flag, aggP);

  // out = tanh(concat(agg, prev) @ Wa^T)  (split-2: tanh-output path)
  const int nwg = (Mp / 128) * 4;
  gemm_mfma<true, true, false><<<nwg, 256, 0, stream>>>(aggP, prevP, WaP, out, N, ND, 32);
}